// Round 1
// baseline (4945.965 us; speedup 1.0000x reference)
//
#include <hip/hip_runtime.h>
#include <cstdint>

typedef float  f32x4  __attribute__((ext_vector_type(4)));
typedef __bf16 bf16x8 __attribute__((ext_vector_type(8)));
typedef unsigned short u16;
typedef u16 u16x8 __attribute__((ext_vector_type(8)));
typedef u16 u16x4 __attribute__((ext_vector_type(4)));

#define TT 512

// ---------- helpers ----------
__device__ __forceinline__ u16 f2bf(float f) {
  unsigned u = __builtin_bit_cast(unsigned, f);
  unsigned r = u + 0x7fffu + ((u >> 16) & 1u);   // RNE
  return (u16)(r >> 16);
}
__device__ __forceinline__ float bf2f(u16 h) {
  unsigned u = ((unsigned)h) << 16;
  return __builtin_bit_cast(float, u);
}
__device__ __forceinline__ float fsig(float x) { return 1.0f / (1.0f + __expf(-x)); }
__device__ __forceinline__ float ftanh(float x) {
  float e = __expf(2.0f * x);
  return 1.0f - 2.0f / (e + 1.0f);
}
__device__ __forceinline__ void gload_lds16(const u16* g, u16* l) {
  __builtin_amdgcn_global_load_lds((const __attribute__((address_space(1))) void*)(g),
                                   (__attribute__((address_space(3))) void*)(l), 16, 0, 0);
}

// ---------- prep: x (N,T,D) fp32 -> xb (T,N,D) bf16 ----------
__global__ __launch_bounds__(256) void prep_x(const float* __restrict__ x, u16* __restrict__ xb) {
  long idx = (long)blockIdx.x * 256 + threadIdx.x;      // 33,554,432 total
  int d = (int)(idx & 255);
  int n = (int)((idx >> 8) & 255);
  int t = (int)(idx >> 16);
  xb[idx] = f2bf(x[((long)n << 17) + ((long)t << 8) + d]);
}

// ---------- prep: weights -> transposed bf16 + bias sum ----------
__global__ __launch_bounds__(256) void prep_w(
    const float* __restrict__ wii, const float* __restrict__ whi,
    const float* __restrict__ wif, const float* __restrict__ whf,
    const float* __restrict__ wig, const float* __restrict__ whg,
    const float* __restrict__ wio, const float* __restrict__ who,
    const float* __restrict__ bii, const float* __restrict__ bhi,
    const float* __restrict__ bif, const float* __restrict__ bhf,
    const float* __restrict__ big_, const float* __restrict__ bhg,
    const float* __restrict__ bio, const float* __restrict__ bho,
    u16* __restrict__ Wxb, u16* __restrict__ Whb, float* __restrict__ bsum) {
  int b = blockIdx.x;
  int tid = threadIdx.x;
  if (b < 1024) {                 // Wxb_t[col][d] = w_x{G}[d][h], col = G*256+h
    const float* wx[4] = {wii, wif, wig, wio};
    int G = b >> 8, h = b & 255;
    Wxb[b * 256 + tid] = f2bf(wx[G][tid * 256 + h]);
  } else if (b < 2048) {          // Whb_t[col][u] = w_h{G}[u][h]
    const float* wh[4] = {whi, whf, whg, who};
    int c = b - 1024;
    int G = c >> 8, h = c & 255;
    Whb[c * 256 + tid] = f2bf(wh[G][tid * 256 + h]);
  } else {
    const float* bx[4] = {bii, bif, big_, bio};
    const float* bh[4] = {bhi, bhf, bhg, bho};
    for (int G = 0; G < 4; ++G) bsum[G * 256 + tid] = bx[G][tid] + bh[G][tid];
  }
}

// ---------- phase 1: xWp = pack(xb @ Wx + b), m97-style 128x128 tile ----------
// Output layout (tile-packed, matches MFMA D layout):
//   xWp[((tm*64 + tn)*256 + lane*4) .. +3] = bf16 of C rows (q*4..q*4+3) col c,
//   where lane = q*16 + c, tm = m/16, tn = n/16.
__global__ __launch_bounds__(256) void gemm_xw(const u16* __restrict__ A, const u16* __restrict__ Bt,
                                               const float* __restrict__ bias, u16* __restrict__ xWp) {
  __shared__ u16 As[128 * 32];
  __shared__ u16 Bs[128 * 32];
  int bid = blockIdx.x;
  int bm = bid & 1023, bn = bid >> 10;    // bm fastest: A-tile unique per bid, B stays hot in L2
  int tid = threadIdx.x;
  int l = tid & 63, w = tid >> 6;
  int wm = w >> 1, wn = w & 1;
  f32x4 acc[4][4];
#pragma unroll
  for (int i = 0; i < 4; ++i)
#pragma unroll
    for (int j = 0; j < 4; ++j) acc[i][j] = (f32x4){0.f, 0.f, 0.f, 0.f};

  const u16* Ab = A + (size_t)bm * 128 * 256;
  const u16* Bb = Bt + (size_t)bn * 128 * 256;
  int row = tid >> 2;
  int ch = tid & 3;
  for (int ko = 0; ko < 8; ++ko) {
    __syncthreads();
    gload_lds16(Ab + (size_t)row * 256 + ko * 32 + ch * 8, As + tid * 8);
    gload_lds16(Ab + (size_t)(row + 64) * 256 + ko * 32 + ch * 8, As + 2048 + tid * 8);
    gload_lds16(Bb + (size_t)row * 256 + ko * 32 + ch * 8, Bs + tid * 8);
    gload_lds16(Bb + (size_t)(row + 64) * 256 + ko * 32 + ch * 8, Bs + 2048 + tid * 8);
    __syncthreads();
    bf16x8 af[4], bfr[4];
#pragma unroll
    for (int mt = 0; mt < 4; ++mt)
      af[mt] = *reinterpret_cast<const bf16x8*>(As + (wm * 64 + mt * 16 + (l & 15)) * 32 + (l >> 4) * 8);
#pragma unroll
    for (int nt = 0; nt < 4; ++nt)
      bfr[nt] = *reinterpret_cast<const bf16x8*>(Bs + (wn * 64 + nt * 16 + (l & 15)) * 32 + (l >> 4) * 8);
#pragma unroll
    for (int mt = 0; mt < 4; ++mt)
#pragma unroll
      for (int nt = 0; nt < 4; ++nt)
        acc[mt][nt] = __builtin_amdgcn_mfma_f32_16x16x32_bf16(af[mt], bfr[nt], acc[mt][nt], 0, 0, 0);
  }
#pragma unroll
  for (int mt = 0; mt < 4; ++mt) {
    int tm = bm * 8 + wm * 4 + mt;
#pragma unroll
    for (int nt = 0; nt < 4; ++nt) {
      int tn = bn * 8 + wn * 4 + nt;
      float bv = bias[tn * 16 + (l & 15)];
      u16x4 pk;
#pragma unroll
      for (int r = 0; r < 4; ++r) pk[r] = f2bf(acc[mt][nt][r] + bv);
      *reinterpret_cast<u16x4*>(xWp + ((size_t)(tm * 64 + tn) * 256 + l * 4)) = pk;
    }
  }
}

// ---------- phase 2: recurrence. 64 groups x 4 wgs; wg owns 64 hidden units ----------
__global__ __launch_bounds__(256, 1) void lstm_rec(const u16* __restrict__ Whb,
                                                   const u16* __restrict__ xWp,
                                                   u16* __restrict__ Hbuf,
                                                   unsigned* __restrict__ flags,
                                                   float* __restrict__ out) {
  __shared__ u16 hlds[16 * 272];   // h matrix [16 rows(batch, rows 4..15 zero)][272 (256 + pad)]
  int b = blockIdx.x;
  int xcd = b & 7, slot = b >> 3;
  int kwg = slot & 3;
  int g = xcd * 8 + (slot >> 2);   // group id 0..63; batch n = 4g + r
  int tid = threadIdx.x;
  int w = tid >> 6, l = tid & 63;

  for (int i = tid; i < 16 * 272; i += 256) hlds[i] = 0;

  // Wh slice resident in registers: 4 gates x 8 ksteps x bf16x8 = 128 VGPRs
  bf16x8 bw[4][8];
#pragma unroll
  for (int gate = 0; gate < 4; ++gate) {
    int col = gate * 256 + kwg * 64 + w * 16 + (l & 15);
#pragma unroll
    for (int ks = 0; ks < 8; ++ks)
      bw[gate][ks] = *reinterpret_cast<const bf16x8*>(Whb + (size_t)col * 256 + ks * 32 + (l >> 4) * 8);
  }
  float cst[4] = {0.f, 0.f, 0.f, 0.f};
  float hout[4] = {0.f, 0.f, 0.f, 0.f};
  unsigned* gf = flags + g * 4;
  __syncthreads();

  for (int t = 0; t < TT; ++t) {
    // prefetch xW (+bias) for this step — independent of the recurrence, issue before spin
    float xw[4][4];
    if (l < 16) {
      int tm = t * 16 + (g >> 2);
      int q = g & 3;
#pragma unroll
      for (int gate = 0; gate < 4; ++gate) {
        int tn = gate * 16 + kwg * 4 + w;
        u16x4 pk = *reinterpret_cast<const u16x4*>(xWp + ((size_t)(tm * 64 + tn) * 256 + (q * 16 + l) * 4));
#pragma unroll
        for (int r = 0; r < 4; ++r) xw[gate][r] = bf2f(pk[r]);
      }
    }
    if (t > 0) {
      if (w == 0) {  // wave 0 spins; acquire fence publishes peer h + invalidates caches
        int guard = 0;
        for (;;) {
          unsigned f0 = __hip_atomic_load(gf + 0, __ATOMIC_RELAXED, __HIP_MEMORY_SCOPE_AGENT);
          unsigned f1 = __hip_atomic_load(gf + 1, __ATOMIC_RELAXED, __HIP_MEMORY_SCOPE_AGENT);
          unsigned f2 = __hip_atomic_load(gf + 2, __ATOMIC_RELAXED, __HIP_MEMORY_SCOPE_AGENT);
          unsigned f3 = __hip_atomic_load(gf + 3, __ATOMIC_RELAXED, __HIP_MEMORY_SCOPE_AGENT);
          if ((f0 >= (unsigned)t && f1 >= (unsigned)t && f2 >= (unsigned)t && f3 >= (unsigned)t) ||
              ++guard > 10000000) break;
        }
        __builtin_amdgcn_fence(__ATOMIC_ACQUIRE, "agent");
      }
      __syncthreads();
      if (tid < 128) {           // load all 4 h-slices of h_{t-1} into hlds rows 0..3
        int r = tid >> 5;
        int j = (tid & 31) * 8;
        const u16* src = Hbuf + (size_t)(g * 2 + ((t + 1) & 1)) * 1024 + (j >> 6) * 256 + r * 64 + (j & 63);
        *reinterpret_cast<u16x8*>(hlds + r * 272 + j) = *reinterpret_cast<const u16x8*>(src);
      }
      __syncthreads();
    }
    f32x4 acc[4];
#pragma unroll
    for (int gate = 0; gate < 4; ++gate) acc[gate] = (f32x4){0.f, 0.f, 0.f, 0.f};
#pragma unroll
    for (int ks = 0; ks < 8; ++ks) {
      bf16x8 a = *reinterpret_cast<const bf16x8*>(hlds + (l & 15) * 272 + ks * 32 + (l >> 4) * 8);
#pragma unroll
      for (int gate = 0; gate < 4; ++gate)
        acc[gate] = __builtin_amdgcn_mfma_f32_16x16x32_bf16(a, bw[gate][ks], acc[gate], 0, 0, 0);
    }
    if (l < 16) {
      u16* hdst = Hbuf + (size_t)(g * 2 + (t & 1)) * 1024 + kwg * 256 + w * 16 + l;
#pragma unroll
      for (int r = 0; r < 4; ++r) {
        float gi = fsig(acc[0][r] + xw[0][r]);
        float gf_ = fsig(acc[1][r] + xw[1][r]);
        float gg = ftanh(acc[2][r] + xw[2][r]);
        float go = fsig(acc[3][r] + xw[3][r]);
        float c = gf_ * cst[r] + gi * gg;
        cst[r] = c;
        float h = go * ftanh(c);
        hout[r] = h;
        hdst[r * 64] = f2bf(h);
      }
    }
    __syncthreads();   // drains all waves' Hbuf stores (vmcnt(0) before s_barrier)
    if (tid == 0) {
      __builtin_amdgcn_fence(__ATOMIC_RELEASE, "agent");
      __hip_atomic_store(gf + kwg, (unsigned)(t + 1), __ATOMIC_RELAXED, __HIP_MEMORY_SCOPE_AGENT);
    }
  }
  if (l < 16) {
#pragma unroll
    for (int r = 0; r < 4; ++r) {
      int n = g * 4 + r;
      int j = kwg * 64 + w * 16 + l;
      out[(size_t)n * 256 + j] = hout[r];
      out[65536 + (size_t)n * 256 + j] = cst[r];
    }
  }
}

// ---------- launch ----------
extern "C" void kernel_launch(void* const* d_in, const int* in_sizes, int n_in,
                              void* d_out, int out_size, void* d_ws, size_t ws_size,
                              hipStream_t stream) {
  const float* x   = (const float*)d_in[0];
  const float* wii = (const float*)d_in[1];
  const float* whi = (const float*)d_in[2];
  const float* wif = (const float*)d_in[3];
  const float* whf = (const float*)d_in[4];
  const float* wig = (const float*)d_in[5];
  const float* whg = (const float*)d_in[6];
  const float* wio = (const float*)d_in[7];
  const float* who = (const float*)d_in[8];
  const float* bii = (const float*)d_in[9];
  const float* bhi = (const float*)d_in[10];
  const float* bif = (const float*)d_in[11];
  const float* bhf = (const float*)d_in[12];
  const float* big_ = (const float*)d_in[13];
  const float* bhg = (const float*)d_in[14];
  const float* bio = (const float*)d_in[15];
  const float* bho = (const float*)d_in[16];

  char* ws = (char*)d_ws;
  u16*   xb    = (u16*)(ws);                        // 67,108,864 B
  u16*   Wxb   = (u16*)(ws + 67108864);             //    524,288 B
  u16*   Whb   = (u16*)(ws + 67633152);             //    524,288 B
  float* bsum  = (float*)(ws + 68157440);           //      4,096 B
  unsigned* flags = (unsigned*)(ws + 68161536);     //      1,024 B
  u16*   Hbuf  = (u16*)(ws + 68165632);             //    262,144 B
  u16*   xWp   = (u16*)(ws + 68427776);             // 268,435,456 B  (total ~321.3 MB)
  float* out = (float*)d_out;

  hipMemsetAsync(flags, 0, 64 * 4 * sizeof(unsigned), stream);
  prep_x<<<131072, 256, 0, stream>>>(x, xb);
  prep_w<<<2049, 256, 0, stream>>>(wii, whi, wif, whf, wig, whg, wio, who,
                                   bii, bhi, bif, bhf, big_, bhg, bio, bho, Wxb, Whb, bsum);
  gemm_xw<<<8192, 256, 0, stream>>>(xb, Wxb, bsum, xWp);

  void* args[5];
  const u16* WhbA = Whb; const u16* xWpA = xWp; u16* HbufA = Hbuf;
  unsigned* flagsA = flags; float* outA = out;
  args[0] = (void*)&WhbA;
  args[1] = (void*)&xWpA;
  args[2] = (void*)&HbufA;
  args[3] = (void*)&flagsA;
  args[4] = (void*)&outA;
  hipLaunchCooperativeKernel((const void*)lstm_rec, dim3(256), dim3(256), args, 0, stream);
}

// Round 2
// 2203.319 us; speedup vs baseline: 2.2448x; 2.2448x over previous
//
#include <hip/hip_runtime.h>
#include <cstdint>

typedef float  f32x4  __attribute__((ext_vector_type(4)));
typedef __bf16 bf16x8 __attribute__((ext_vector_type(8)));
typedef int    i32x4  __attribute__((ext_vector_type(4)));
typedef unsigned short u16;
typedef u16 u16x4 __attribute__((ext_vector_type(4)));

#define TT 512

// ---------- helpers ----------
__device__ __forceinline__ u16 f2bf(float f) {
  unsigned u = __builtin_bit_cast(unsigned, f);
  unsigned r = u + 0x7fffu + ((u >> 16) & 1u);   // RNE
  return (u16)(r >> 16);
}
__device__ __forceinline__ float bflo(unsigned d) { return __builtin_bit_cast(float, d << 16); }
__device__ __forceinline__ float bfhi(unsigned d) { return __builtin_bit_cast(float, d & 0xffff0000u); }
__device__ __forceinline__ float rcpf(float x) { return __builtin_amdgcn_rcpf(x); }
__device__ __forceinline__ float fsig(float x) { return rcpf(1.f + __expf(-x)); }
__device__ __forceinline__ float ftanh(float x) { return 1.f - 2.f * rcpf(1.f + __expf(2.f * x)); }
__device__ __forceinline__ void gload_lds16(const u16* g, u16* l) {
  __builtin_amdgcn_global_load_lds((const __attribute__((address_space(1))) void*)(g),
                                   (__attribute__((address_space(3))) void*)(l), 16, 0, 0);
}

// ---------- prep: x (N,T,D) fp32 -> xb (T,N,D) bf16, 4 elems/thread ----------
__global__ __launch_bounds__(256) void prep_x(const float* __restrict__ x, u16* __restrict__ xb) {
  long o = ((long)blockIdx.x * 256 + threadIdx.x) * 4;   // 33,554,432 total elems
  int d = (int)(o & 255);
  int n = (int)((o >> 8) & 255);
  int t = (int)(o >> 16);
  const float4 v = *(const float4*)(x + ((long)n << 17) + ((long)t << 8) + d);
  u16x4 p;
  p[0] = f2bf(v.x); p[1] = f2bf(v.y); p[2] = f2bf(v.z); p[3] = f2bf(v.w);
  *(u16x4*)(xb + o) = p;
}

// ---------- prep: Wx -> bf16 transposed; Wh -> i8 per-col quant; bias sum ----------
__global__ __launch_bounds__(256) void prep_w(
    const float* __restrict__ wii, const float* __restrict__ whi,
    const float* __restrict__ wif, const float* __restrict__ whf,
    const float* __restrict__ wig, const float* __restrict__ whg,
    const float* __restrict__ wio, const float* __restrict__ who,
    const float* __restrict__ bii, const float* __restrict__ bhi,
    const float* __restrict__ bif, const float* __restrict__ bhf,
    const float* __restrict__ big_, const float* __restrict__ bhg,
    const float* __restrict__ bio, const float* __restrict__ bho,
    u16* __restrict__ Wxb, signed char* __restrict__ Whq,
    float* __restrict__ wscale, float* __restrict__ bsum) {
  __shared__ float red[256];
  int b = blockIdx.x;
  int tid = threadIdx.x;
  if (b < 1024) {                 // Wxb_t[col][d] = w_x{G}[d][h], col = G*256+h
    const float* wx[4] = {wii, wif, wig, wio};
    int G = b >> 8, h = b & 255;
    Wxb[b * 256 + tid] = f2bf(wx[G][tid * 256 + h]);
  } else if (b < 2048) {          // Whq[col][u] = quant(w_h{G}[u][h]), per-col scale
    const float* wh[4] = {whi, whf, whg, who};
    int cidx = b - 1024;
    int G = cidx >> 8, h = cidx & 255;
    float w = wh[G][tid * 256 + h];
    red[tid] = fabsf(w);
    __syncthreads();
    for (int s = 128; s > 0; s >>= 1) {
      if (tid < s) red[tid] = fmaxf(red[tid], red[tid + s]);
      __syncthreads();
    }
    float mx = red[0];
    float scale = (mx > 0.f) ? mx * (1.f / 127.f) : 1.f;
    float qf = rintf(w / scale);
    qf = fminf(127.f, fmaxf(-127.f, qf));
    Whq[cidx * 256 + tid] = (signed char)(int)qf;
    if (tid == 0) wscale[cidx] = scale * (1.f / 127.f);   // combined w-scale * h-scale
  } else {
    const float* bx[4] = {bii, bif, big_, bio};
    const float* bh[4] = {bhi, bhf, bhg, bho};
    for (int G = 0; G < 4; ++G) bsum[G * 256 + tid] = bx[G][tid] + bh[G][tid];
  }
}

// ---------- phase 1: xWp = pack(xb @ Wx + b), m97-style 128x128 tile ----------
// Output tile-packed (MFMA C layout): xWp[(tm*64+tn)*256 + l*4 + r],
// lane l = q*16+c -> rows q*4+r, col c of tile (tm,tn).
__global__ __launch_bounds__(256) void gemm_xw(const u16* __restrict__ A, const u16* __restrict__ Bt,
                                               const float* __restrict__ bias, u16* __restrict__ xWp) {
  __shared__ u16 As[128 * 32];
  __shared__ u16 Bs[128 * 32];
  int bid = blockIdx.x;
  int bm = bid & 1023, bn = bid >> 10;
  int tid = threadIdx.x;
  int l = tid & 63, w = tid >> 6;
  int wm = w >> 1, wn = w & 1;
  f32x4 acc[4][4];
#pragma unroll
  for (int i = 0; i < 4; ++i)
#pragma unroll
    for (int j = 0; j < 4; ++j) acc[i][j] = (f32x4){0.f, 0.f, 0.f, 0.f};

  const u16* Ab = A + (size_t)bm * 128 * 256;
  const u16* Bb = Bt + (size_t)bn * 128 * 256;
  int row = tid >> 2;
  int ch = tid & 3;
  for (int ko = 0; ko < 8; ++ko) {
    __syncthreads();
    gload_lds16(Ab + (size_t)row * 256 + ko * 32 + ch * 8, As + tid * 8);
    gload_lds16(Ab + (size_t)(row + 64) * 256 + ko * 32 + ch * 8, As + 2048 + tid * 8);
    gload_lds16(Bb + (size_t)row * 256 + ko * 32 + ch * 8, Bs + tid * 8);
    gload_lds16(Bb + (size_t)(row + 64) * 256 + ko * 32 + ch * 8, Bs + 2048 + tid * 8);
    __syncthreads();
    bf16x8 af[4], bfr[4];
#pragma unroll
    for (int mt = 0; mt < 4; ++mt)
      af[mt] = *reinterpret_cast<const bf16x8*>(As + (wm * 64 + mt * 16 + (l & 15)) * 32 + (l >> 4) * 8);
#pragma unroll
    for (int nt = 0; nt < 4; ++nt)
      bfr[nt] = *reinterpret_cast<const bf16x8*>(Bs + (wn * 64 + nt * 16 + (l & 15)) * 32 + (l >> 4) * 8);
#pragma unroll
    for (int mt = 0; mt < 4; ++mt)
#pragma unroll
      for (int nt = 0; nt < 4; ++nt)
        acc[mt][nt] = __builtin_amdgcn_mfma_f32_16x16x32_bf16(af[mt], bfr[nt], acc[mt][nt], 0, 0, 0);
  }
#pragma unroll
  for (int mt = 0; mt < 4; ++mt) {
    int tm = bm * 8 + wm * 4 + mt;
#pragma unroll
    for (int nt = 0; nt < 4; ++nt) {
      int tn = bn * 8 + wn * 4 + nt;
      float bv = bias[tn * 16 + (l & 15)];
      u16x4 pk;
#pragma unroll
      for (int r = 0; r < 4; ++r) pk[r] = f2bf(acc[mt][nt][r] + bv);
      *reinterpret_cast<u16x4*>(xWp + ((size_t)(tm * 64 + tn) * 256 + l * 4)) = pk;
    }
  }
}

// ---------- phase 2: recurrence, fully CU-local ----------
// 64 wgs x 512 threads (8 waves). wg b owns batch rows b*4..b*4+3 (independent chains).
// Wave wid owns hidden units wid*32..wid*32+31 for all 4 gates: Wh i8 slice in
// 128 VGPRs/lane. h_t kept in LDS as i8 (4 rows x 256), double-buffered.
// A rows replicated (row = (lane&15)&3) so every quad of the 16x16 C tile holds
// all 4 batch rows -> each lane owns 2 cells, no cross-lane shuffles.
// Raw s_barrier with lgkmcnt-only wait keeps xW prefetch loads in flight.
__global__ __launch_bounds__(512, 2) void lstm_rec(const signed char* __restrict__ Whq,
                                                   const float* __restrict__ wscale,
                                                   const u16* __restrict__ xWp,
                                                   float* __restrict__ out) {
  __shared__ __align__(16) signed char hb[2][4 * 272];   // 2 x (4 rows x 272B)
  int b = blockIdx.x;            // 0..63
  int tid = threadIdx.x;
  int wid = tid >> 6, l = tid & 63;
  int c = l & 15, q = (l >> 4) & 3;
  int tt = q >> 1, rsel = q & 1;

  for (int i = tid; i < 2 * 1088 / 4; i += 512) ((int*)hb)[i] = 0;

  // Wh i8 fragments: [gate][tt-tile][kstep], 16B each = 128 VGPRs
  i32x4 bw[4][2][4];
#pragma unroll
  for (int g = 0; g < 4; ++g)
#pragma unroll
    for (int ttl = 0; ttl < 2; ++ttl) {
      int col = g * 256 + wid * 32 + ttl * 16 + c;
#pragma unroll
      for (int ks = 0; ks < 4; ++ks)
        bw[g][ttl][ks] = *reinterpret_cast<const i32x4*>(Whq + (size_t)col * 256 + ks * 64 + q * 16);
    }
  float sc8[4];
#pragma unroll
  for (int g = 0; g < 4; ++g) sc8[g] = wscale[g * 256 + wid * 32 + tt * 16 + c];

  // xW addressing: byte base for step t = (t*16 + b/4)*32768
  const char* xbase = (const char*)xWp + (size_t)(b >> 2) * 32768;
  int xoff[4];
#pragma unroll
  for (int g = 0; g < 4; ++g) {
    int tn = g * 16 + wid * 2 + tt;
    xoff[g] = tn * 512 + ((b & 3) * 16 + c) * 8 + rsel * 4;
  }
  unsigned xw[2][4];
#pragma unroll
  for (int g = 0; g < 4; ++g) xw[0][g] = *(const unsigned*)(xbase + xoff[g]);   // t=0
  xbase += 524288;   // -> t=1

  float cs[2] = {0.f, 0.f}, hh[2] = {0.f, 0.f};
  __syncthreads();

#pragma unroll 2
  for (int t = 0; t < TT; ++t) {
    int cur = t & 1, nxt = cur ^ 1;
    // prefetch xW for t+1 (stays in flight across the barrier)
#pragma unroll
    for (int g = 0; g < 4; ++g) xw[nxt][g] = *(const unsigned*)(xbase + xoff[g]);

    // h_{t-1} fragments (rows replicated via (c&3)) + MFMA
    const signed char* hr = hb[nxt];
    i32x4 acc[4][2];
#pragma unroll
    for (int g = 0; g < 4; ++g)
#pragma unroll
      for (int ttl = 0; ttl < 2; ++ttl) acc[g][ttl] = (i32x4){0, 0, 0, 0};
#pragma unroll
    for (int ks = 0; ks < 4; ++ks) {
      i32x4 a = *reinterpret_cast<const i32x4*>(hr + (c & 3) * 272 + ks * 64 + q * 16);
#pragma unroll
      for (int g = 0; g < 4; ++g) {
        acc[g][0] = __builtin_amdgcn_mfma_i32_16x16x64_i8(a, bw[g][0][ks], acc[g][0], 0, 0, 0);
        acc[g][1] = __builtin_amdgcn_mfma_i32_16x16x64_i8(a, bw[g][1][ks], acc[g][1], 0, 0, 0);
      }
    }

    // elementwise: this lane owns cells (rows 2*rsel+{0,1}, col tt*16+c of wave slice)
    float a4[4][2];
#pragma unroll
    for (int g = 0; g < 4; ++g) {
      i32x4 av = tt ? acc[g][1] : acc[g][0];
      int e0 = rsel ? av[2] : av[0];
      int e1 = rsel ? av[3] : av[1];
      unsigned d = xw[cur][g];
      a4[g][0] = (float)e0 * sc8[g] + bflo(d);
      a4[g][1] = (float)e1 * sc8[g] + bfhi(d);
    }
    signed char* hw = hb[cur];
#pragma unroll
    for (int j = 0; j < 2; ++j) {
      float gi = fsig(a4[0][j]);
      float gf = fsig(a4[1][j]);
      float gg = ftanh(a4[2][j]);
      float go = fsig(a4[3][j]);
      float cc = gf * cs[j] + gi * gg;
      cs[j] = cc;
      float h = go * ftanh(cc);
      hh[j] = h;
      int hq = (int)rintf(h * 127.f);
      hw[(2 * rsel + j) * 272 + wid * 32 + tt * 16 + c] = (signed char)hq;
    }
    xbase += 524288;

    // raw barrier: wait LDS only (lgkmcnt(0)), leave vmcnt in flight
    asm volatile("" ::: "memory");
    __builtin_amdgcn_s_waitcnt(0xC07F);
    __builtin_amdgcn_s_barrier();
    asm volatile("" ::: "memory");
  }

#pragma unroll
  for (int j = 0; j < 2; ++j) {
    int n = b * 4 + 2 * rsel + j;
    int hu = wid * 32 + tt * 16 + c;
    out[(size_t)n * 256 + hu] = hh[j];
    out[65536 + (size_t)n * 256 + hu] = cs[j];
  }
}

// ---------- launch ----------
extern "C" void kernel_launch(void* const* d_in, const int* in_sizes, int n_in,
                              void* d_out, int out_size, void* d_ws, size_t ws_size,
                              hipStream_t stream) {
  const float* x   = (const float*)d_in[0];
  const float* wii = (const float*)d_in[1];
  const float* whi = (const float*)d_in[2];
  const float* wif = (const float*)d_in[3];
  const float* whf = (const float*)d_in[4];
  const float* wig = (const float*)d_in[5];
  const float* whg = (const float*)d_in[6];
  const float* wio = (const float*)d_in[7];
  const float* who = (const float*)d_in[8];
  const float* bii = (const float*)d_in[9];
  const float* bhi = (const float*)d_in[10];
  const float* bif = (const float*)d_in[11];
  const float* bhf = (const float*)d_in[12];
  const float* big_ = (const float*)d_in[13];
  const float* bhg = (const float*)d_in[14];
  const float* bio = (const float*)d_in[15];
  const float* bho = (const float*)d_in[16];

  char* ws = (char*)d_ws;
  u16*   xb     = (u16*)(ws);                         // 67,108,864 B
  u16*   Wxb    = (u16*)(ws + 67108864);              //    524,288 B
  signed char* Whq = (signed char*)(ws + 67633152);   //    262,144 B
  float* wscale = (float*)(ws + 67895296);            //      4,096 B
  float* bsum   = (float*)(ws + 67899392);            //      4,096 B
  u16*   xWp    = (u16*)(ws + 67903488);              // 268,435,456 B + 524,288 B prefetch pad
  float* out = (float*)d_out;

  prep_x<<<32768, 256, 0, stream>>>(x, xb);
  prep_w<<<2049, 256, 0, stream>>>(wii, whi, wif, whf, wig, whg, wio, who,
                                   bii, bhi, bif, bhf, big_, bhg, bio, bho,
                                   Wxb, Whq, wscale, bsum);
  gemm_xw<<<8192, 256, 0, stream>>>(xb, Wxb, bsum, xWp);
  lstm_rec<<<64, 512, 0, stream>>>(Whq, wscale, xWp, out);
}